// Round 5
// baseline (462.966 us; speedup 1.0000x reference)
//
#include <hip/hip_runtime.h>
#include <hip/hip_bf16.h>
#include <math.h>

// VectorQuantizer: z (4,64,32,32,32) f32, embedding (1024,64) f32.
// R4: f16 MFMA prefilter (codebook pre-scaled x1024, whole codebook in LDS,
// fused best/best2/argmin epilogue) + provable per-row margin; flagged rows
// (~8%) re-scored by the bit-exact fp32 reference simulation:
//   d_j = fl32( fl32(A + E_j) - 2*serialFMA(z,e_j) ), pairwise8 sums,
//   np.argmin lowest-index ties.
// R5: refine was latency-starved (VALUBusy 7%, 2 waves/SIMD, 288 us).
//     Only change: refine launch shape -> 1024 blocks x 256 thr, one row per
//     WAVE (4 waves/block -> 4 waves/SIMD saturates the 4-cy FMA dep chain).
//     Score kernel untouched for clean A/B attribution.

#define ENUM 1024
#define EDIM 64
#define SPAT 32768           // 32*32*32
#define NROWS 131072         // 4 * SPAT
#define LDS_STRIDE 72        // halves per code row: 64 data + 2 (esq f32) + pad; 144B, 16B-aligned

typedef _Float16 half8 __attribute__((ext_vector_type(8)));
typedef float f32x4 __attribute__((ext_vector_type(4)));
typedef unsigned short us8 __attribute__((ext_vector_type(8)));

// numpy pairwise_sum for n=64: 8 stride-8 accumulators, then tree combine.
__device__ __forceinline__ float pairwise64(const float* t) {
    float r[8];
#pragma unroll
    for (int l = 0; l < 8; ++l) r[l] = t[l];
#pragma unroll
    for (int i = 8; i < 64; i += 8) {
#pragma unroll
        for (int l = 0; l < 8; ++l) r[l] = __fadd_rn(r[l], t[i + l]);
    }
    return __fadd_rn(__fadd_rn(__fadd_rn(r[0], r[1]), __fadd_rn(r[2], r[3])),
                     __fadd_rn(__fadd_rn(r[4], r[5]), __fadd_rn(r[6], r[7])));
}

// ---------------------------------------------------------------- prep -----
// One block, 1024 threads: exact esq (ref pairwise replica), f16 codebook
// scaled x1024, max(esq) for the margin, zero the refine counter.
__global__ __launch_bounds__(1024) void vq_prep(const float* __restrict__ emb,
                                                float* __restrict__ esq_g,
                                                _Float16* __restrict__ ef,
                                                float* __restrict__ maxesq,
                                                unsigned int* __restrict__ cnt) {
    __shared__ float red[1024];
    int j = threadIdx.x;
    const float4* ep = reinterpret_cast<const float4*>(emb + j * EDIM);
    float t[EDIM];
#pragma unroll
    for (int kk = 0; kk < 16; ++kk) {
        float4 v = ep[kk];
        t[4 * kk + 0] = __fmul_rn(v.x, v.x);
        t[4 * kk + 1] = __fmul_rn(v.y, v.y);
        t[4 * kk + 2] = __fmul_rn(v.z, v.z);
        t[4 * kk + 3] = __fmul_rn(v.w, v.w);
        ef[j * EDIM + 4 * kk + 0] = (_Float16)(v.x * 1024.0f);
        ef[j * EDIM + 4 * kk + 1] = (_Float16)(v.y * 1024.0f);
        ef[j * EDIM + 4 * kk + 2] = (_Float16)(v.z * 1024.0f);
        ef[j * EDIM + 4 * kk + 3] = (_Float16)(v.w * 1024.0f);
    }
    float e2 = pairwise64(t);
    esq_g[j] = e2;
    red[j] = e2;
    __syncthreads();
    for (int s = 512; s > 0; s >>= 1) {
        if (j < s) red[j] = fmaxf(red[j], red[j + s]);
        __syncthreads();
    }
    if (j == 0) { *maxesq = red[0]; *cnt = 0u; }
}

// ------------------------------------------------------------- score -------
// 256 blocks x 1024 thr (16 waves). Whole codebook (f16, x1024) + esq in LDS.
// Each wave: 2 row-tiles of 16 rows; per row-tile iterate 64 col-tiles:
// 2x mfma_f32_16x16x32_f16 (K=64) + fused best/best2/argmin epilogue.
// A-frag: lane l -> row l%16, k = (l/16)*8 + i  (i=0..7 contiguous).
// B-frag: lane l -> col l%16, k = (l/16)*8 + i  -> e'[col][k] contiguous 16B.
// C:      lane l, reg q -> row (l/16)*4+q, col l%16  (m89-verified).
__global__ __launch_bounds__(1024, 4) void vq_score(const float* __restrict__ z,
                                                    const _Float16* __restrict__ ef,
                                                    const float* __restrict__ esq_g,
                                                    const float* __restrict__ maxesq,
                                                    int* __restrict__ idx,
                                                    int* __restrict__ list,
                                                    unsigned int* __restrict__ cnt) {
    __shared__ __align__(16) unsigned short eL[ENUM * LDS_STRIDE];  // 147456 B

    int tid = threadIdx.x;
    // ---- stage codebook + esq into LDS (code j = tid) ----
    {
        const unsigned short* src = reinterpret_cast<const unsigned short*>(ef) + tid * EDIM;
#pragma unroll
        for (int i = 0; i < 8; ++i)
            *reinterpret_cast<us8*>(&eL[tid * LDS_STRIDE + i * 8]) =
                *reinterpret_cast<const us8*>(src + i * 8);
        *reinterpret_cast<float*>(&eL[tid * LDS_STRIDE + 64]) = esq_g[tid];
    }
    __syncthreads();

    int l  = tid & 63;
    int w  = tid >> 6;          // wave 0..15
    int g  = l >> 4;            // k-group 0..3
    int li = l & 15;            // row (A) / col (B) within tile
    float mxe = *maxesq;

    for (int c = 0; c < 2; ++c) {
        int rt0 = blockIdx.x * 512 + w * 32 + c * 16;   // row-tile base
        int b = rt0 >> 15;
        int s0 = (rt0 & (SPAT - 1)) + li;
        const float* zp = z + (size_t)b * EDIM * SPAT + s0;
        int o = g * 8;

        float za[8], zb8[8];
#pragma unroll
        for (int i = 0; i < 8; ++i) za[i]  = zp[(size_t)(o + i) * SPAT];
#pragma unroll
        for (int i = 0; i < 8; ++i) zb8[i] = zp[(size_t)(32 + o + i) * SPAT];

        // ||z||^2 partial -> full (groups hold disjoint k-octets)
        float pa = 0.f;
#pragma unroll
        for (int i = 0; i < 8; ++i) pa += za[i] * za[i] + zb8[i] * zb8[i];
        pa += __shfl_xor(pa, 16);
        pa += __shfl_xor(pa, 32);

        half8 fa0, fa1;
#pragma unroll
        for (int i = 0; i < 8; ++i) { fa0[i] = (_Float16)za[i]; fa1[i] = (_Float16)zb8[i]; }

        // per-q sound margin: 2^-8 * sqrt(A*max||e||^2) + 3e-5
        float mrg[4];
#pragma unroll
        for (int q = 0; q < 4; ++q) {
            float Aq = __shfl(pa, g * 4 + q);
            mrg[q] = fmaf(sqrtf(Aq * mxe), 0.00390625f, 3.0e-5f);
        }

        float best[4], best2[4];
        int bidx[4];
#pragma unroll
        for (int q = 0; q < 4; ++q) { best[q] = 3.4e38f; best2[q] = 3.4e38f; bidx[q] = 0; }

        for (int ct = 0; ct < 64; ++ct) {
            int code = ct * 16 + li;
            int base = code * LDS_STRIDE + g * 8;
            half8 fb0 = *reinterpret_cast<const half8*>(&eL[base]);
            half8 fb1 = *reinterpret_cast<const half8*>(&eL[base + 32]);
            float esqv = *reinterpret_cast<const float*>(&eL[code * LDS_STRIDE + 64]);
            f32x4 acc = {0.f, 0.f, 0.f, 0.f};
            acc = __builtin_amdgcn_mfma_f32_16x16x32_f16(fa0, fb0, acc, 0, 0, 0);
            acc = __builtin_amdgcn_mfma_f32_16x16x32_f16(fa1, fb1, acc, 0, 0, 0);
#pragma unroll
            for (int q = 0; q < 4; ++q) {
                float sc = fmaf(-0.001953125f, acc[q], esqv);   // esq - 2^-9 * dot'
                bool lt = sc < best[q];
                best2[q] = fminf(best2[q], fmaxf(best[q], sc));
                best[q]  = fminf(best[q], sc);
                bidx[q]  = lt ? code : bidx[q];
            }
        }

        // merge across the 16 col-lanes of this row-group
#pragma unroll
        for (int off = 1; off < 16; off <<= 1) {
#pragma unroll
            for (int q = 0; q < 4; ++q) {
                float nb  = __shfl_xor(best[q], off);
                float nb2 = __shfl_xor(best2[q], off);
                int   nj  = __shfl_xor(bidx[q], off);
                best2[q] = fminf(fminf(best2[q], nb2), fmaxf(best[q], nb));
                bool tk = nb < best[q];
                best[q] = fminf(best[q], nb);
                bidx[q] = tk ? nj : bidx[q];
            }
        }

        if (li < 4) {
            int q = li;
            int row = rt0 + g * 4 + q;
            idx[row] = bidx[q];
            if (best2[q] - best[q] <= mrg[q]) {
                unsigned int p = atomicAdd(cnt, 1u);
                list[p] = row;
            }
        }
    }
}

// ------------------------------------------------------------ refine -------
// One wave per flagged row (compacted list); 4 waves/block so the 4-cycle
// serial-FMA dependency is hidden by TLP (R5 change: launch shape only).
// EXACT fp32 simulation of the reference: serial single-accumulator fmaf
// chain (sgemm micro-kernel order). Lexicographic (d, j) = np.argmin.
__global__ __launch_bounds__(256, 4) void vq_refine(const float* __restrict__ z,
                                                    const float* __restrict__ emb,
                                                    const float* __restrict__ esq,
                                                    const int* __restrict__ list,
                                                    const unsigned int* __restrict__ cnt,
                                                    int* __restrict__ idx) {
    int lane = threadIdx.x & 63;
    int wv   = threadIdx.x >> 6;                // wave within block (0..3)
    unsigned int n = *cnt;
    for (unsigned int i = blockIdx.x * 4 + wv; i < n; i += gridDim.x * 4) {
        int row = list[i];
        int b = row >> 15;
        int s = row & (SPAT - 1);
        const float* zb = z + (size_t)b * EDIM * SPAT + s;
        float zr[EDIM];
#pragma unroll
        for (int c = 0; c < EDIM; ++c) zr[c] = zb[(size_t)c * SPAT];
        float zsq[EDIM];
#pragma unroll
        for (int c = 0; c < EDIM; ++c) zsq[c] = __fmul_rn(zr[c], zr[c]);
        float A = pairwise64(zsq);

        float bd = 3.4e38f;
        int bj = 0;
#pragma unroll 2
        for (int t = 0; t < ENUM / 64; ++t) {   // ascending j within lane
            int j = lane + 64 * t;
            const float* ej = emb + j * EDIM;
            float acc = 0.f;
#pragma unroll
            for (int k = 0; k < EDIM; ++k)
                acc = fmaf(zr[k], ej[k], acc);  // serial FMA, sgemm order
            float tmp = __fadd_rn(A, esq[j]);
            float d = fmaf(-2.f, acc, tmp);     // bit-exact reference d_j
            if (d < bd) { bd = d; bj = j; }     // strict < keeps lowest j
        }
#pragma unroll
        for (int off = 32; off > 0; off >>= 1) {
            float od = __shfl_down(bd, off, 64);
            int oj = __shfl_down(bj, off, 64);
            if (od < bd || (od == bd && oj < bj)) { bd = od; bj = oj; }
        }
        if (lane == 0) idx[row] = bj;
    }
}

// ------------------------------------------------------------ gather -------
__global__ __launch_bounds__(256) void vq_gather(const float* __restrict__ emb,
                                                 const int* __restrict__ idx,
                                                 float* __restrict__ out) {
    int row = blockIdx.x * 256 + threadIdx.x;
    int b = row >> 15;
    int s = row & (SPAT - 1);
    int j = idx[row];
    const float4* e4 = reinterpret_cast<const float4*>(emb + j * EDIM);
    float ev[EDIM];
#pragma unroll
    for (int k = 0; k < EDIM / 4; ++k) {
        float4 v = e4[k];
        ev[4 * k + 0] = v.x; ev[4 * k + 1] = v.y;
        ev[4 * k + 2] = v.z; ev[4 * k + 3] = v.w;
    }
    float* ob = out + (size_t)b * EDIM * SPAT + s;
#pragma unroll
    for (int c = 0; c < EDIM; ++c) ob[(size_t)c * SPAT] = ev[c];  // coalesced per c
}

// ------------------------------------------------------------ launch -------
extern "C" void kernel_launch(void* const* d_in, const int* in_sizes, int n_in,
                              void* d_out, int out_size, void* d_ws, size_t ws_size,
                              hipStream_t stream) {
    const float* z   = (const float*)d_in[0];
    const float* emb = (const float*)d_in[1];
    float* out = (float*)d_out;

    // ws: esq f32[1024] | maxesq f32 | cnt u32 (pad to 4KB) | ef f16[1024*64]
    //     | idx i32[NROWS] | list i32[NROWS]   (~1.16 MB)
    char* wp = (char*)d_ws;
    float* esq = (float*)wp;                       wp += 4096;
    float* mxe = (float*)wp;
    unsigned int* cnt = (unsigned int*)(wp + 16);  wp += 4096;
    _Float16* ef = (_Float16*)wp;                  wp += sizeof(_Float16) * ENUM * EDIM;
    int* idx = (int*)wp;                           wp += sizeof(int) * (size_t)NROWS;
    int* list = (int*)wp;

    vq_prep  <<<1,           1024, 0, stream>>>(emb, esq, ef, mxe, cnt);
    vq_score <<<256,         1024, 0, stream>>>(z, ef, esq, mxe, idx, list, cnt);
    vq_refine<<<1024,         256, 0, stream>>>(z, emb, esq, list, cnt, idx);
    vq_gather<<<NROWS / 256,  256, 0, stream>>>(emb, idx, out);
}

// Round 6
// 321.475 us; speedup vs baseline: 1.4401x; 1.4401x over previous
//
#include <hip/hip_runtime.h>
#include <hip/hip_bf16.h>
#include <math.h>

// VectorQuantizer: z (4,64,32,32,32) f32, embedding (1024,64) f32.
// R4: f16 MFMA prefilter (codebook pre-scaled x1024, whole codebook in LDS,
// fused best/best2/argmin epilogue) + provable per-row margin; flagged rows
// (~8%) re-scored by the bit-exact fp32 reference simulation:
//   d_j = fl32( fl32(A + E_j) - 2*serialFMA(z,e_j) ), pairwise8 sums,
//   np.argmin lowest-index ties.
// R6: refine was SCRATCH-bound, not TLP-bound (VGPR=52 but zr[64]+zsq[64]
//   live => spilled; serial FMA chain re-read zr from scratch at L2 latency;
//   VALUBusy 7.5% at both 20% and 40% occupancy). Rewrite:
//   - z-row is wave-uniform -> readfirstlane into 64 SGPRs (no VGPR arrays);
//   - A computed streaming (bit-identical op order, never 128 live temps);
//   - codebook staged in LDS tiles of 128 codes (stride 66 dwords, 2-way
//     bank alias = free), shared by 4 rows/block -> 4x less L2 traffic.

#define ENUM 1024
#define EDIM 64
#define SPAT 32768           // 32*32*32
#define NROWS 131072         // 4 * SPAT
#define LDS_STRIDE 72        // score: halves per code row (64 data + esq + pad)

typedef _Float16 half8 __attribute__((ext_vector_type(8)));
typedef float f32x4 __attribute__((ext_vector_type(4)));
typedef unsigned short us8 __attribute__((ext_vector_type(8)));

__device__ __forceinline__ float uniform_f32(float v) {
    return __int_as_float(__builtin_amdgcn_readfirstlane(__float_as_int(v)));
}

// numpy pairwise_sum for n=64: 8 stride-8 accumulators, then tree combine.
__device__ __forceinline__ float pairwise64(const float* t) {
    float r[8];
#pragma unroll
    for (int l = 0; l < 8; ++l) r[l] = t[l];
#pragma unroll
    for (int i = 8; i < 64; i += 8) {
#pragma unroll
        for (int l = 0; l < 8; ++l) r[l] = __fadd_rn(r[l], t[i + l]);
    }
    return __fadd_rn(__fadd_rn(__fadd_rn(r[0], r[1]), __fadd_rn(r[2], r[3])),
                     __fadd_rn(__fadd_rn(r[4], r[5]), __fadd_rn(r[6], r[7])));
}

// ---------------------------------------------------------------- prep -----
__global__ __launch_bounds__(1024) void vq_prep(const float* __restrict__ emb,
                                                float* __restrict__ esq_g,
                                                _Float16* __restrict__ ef,
                                                float* __restrict__ maxesq,
                                                unsigned int* __restrict__ cnt) {
    __shared__ float red[1024];
    int j = threadIdx.x;
    const float4* ep = reinterpret_cast<const float4*>(emb + j * EDIM);
    float t[EDIM];
#pragma unroll
    for (int kk = 0; kk < 16; ++kk) {
        float4 v = ep[kk];
        t[4 * kk + 0] = __fmul_rn(v.x, v.x);
        t[4 * kk + 1] = __fmul_rn(v.y, v.y);
        t[4 * kk + 2] = __fmul_rn(v.z, v.z);
        t[4 * kk + 3] = __fmul_rn(v.w, v.w);
        ef[j * EDIM + 4 * kk + 0] = (_Float16)(v.x * 1024.0f);
        ef[j * EDIM + 4 * kk + 1] = (_Float16)(v.y * 1024.0f);
        ef[j * EDIM + 4 * kk + 2] = (_Float16)(v.z * 1024.0f);
        ef[j * EDIM + 4 * kk + 3] = (_Float16)(v.w * 1024.0f);
    }
    float e2 = pairwise64(t);
    esq_g[j] = e2;
    red[j] = e2;
    __syncthreads();
    for (int s = 512; s > 0; s >>= 1) {
        if (j < s) red[j] = fmaxf(red[j], red[j + s]);
        __syncthreads();
    }
    if (j == 0) { *maxesq = red[0]; *cnt = 0u; }
}

// ------------------------------------------------------------- score -------
// (unchanged from R4/R5 — counters pending)
__global__ __launch_bounds__(1024, 4) void vq_score(const float* __restrict__ z,
                                                    const _Float16* __restrict__ ef,
                                                    const float* __restrict__ esq_g,
                                                    const float* __restrict__ maxesq,
                                                    int* __restrict__ idx,
                                                    int* __restrict__ list,
                                                    unsigned int* __restrict__ cnt) {
    __shared__ __align__(16) unsigned short eL[ENUM * LDS_STRIDE];  // 147456 B

    int tid = threadIdx.x;
    {
        const unsigned short* src = reinterpret_cast<const unsigned short*>(ef) + tid * EDIM;
#pragma unroll
        for (int i = 0; i < 8; ++i)
            *reinterpret_cast<us8*>(&eL[tid * LDS_STRIDE + i * 8]) =
                *reinterpret_cast<const us8*>(src + i * 8);
        *reinterpret_cast<float*>(&eL[tid * LDS_STRIDE + 64]) = esq_g[tid];
    }
    __syncthreads();

    int l  = tid & 63;
    int w  = tid >> 6;          // wave 0..15
    int g  = l >> 4;            // k-group 0..3
    int li = l & 15;            // row (A) / col (B) within tile
    float mxe = *maxesq;

    for (int c = 0; c < 2; ++c) {
        int rt0 = blockIdx.x * 512 + w * 32 + c * 16;   // row-tile base
        int b = rt0 >> 15;
        int s0 = (rt0 & (SPAT - 1)) + li;
        const float* zp = z + (size_t)b * EDIM * SPAT + s0;
        int o = g * 8;

        float za[8], zb8[8];
#pragma unroll
        for (int i = 0; i < 8; ++i) za[i]  = zp[(size_t)(o + i) * SPAT];
#pragma unroll
        for (int i = 0; i < 8; ++i) zb8[i] = zp[(size_t)(32 + o + i) * SPAT];

        float pa = 0.f;
#pragma unroll
        for (int i = 0; i < 8; ++i) pa += za[i] * za[i] + zb8[i] * zb8[i];
        pa += __shfl_xor(pa, 16);
        pa += __shfl_xor(pa, 32);

        half8 fa0, fa1;
#pragma unroll
        for (int i = 0; i < 8; ++i) { fa0[i] = (_Float16)za[i]; fa1[i] = (_Float16)zb8[i]; }

        float mrg[4];
#pragma unroll
        for (int q = 0; q < 4; ++q) {
            float Aq = __shfl(pa, g * 4 + q);
            mrg[q] = fmaf(sqrtf(Aq * mxe), 0.00390625f, 3.0e-5f);
        }

        float best[4], best2[4];
        int bidx[4];
#pragma unroll
        for (int q = 0; q < 4; ++q) { best[q] = 3.4e38f; best2[q] = 3.4e38f; bidx[q] = 0; }

        for (int ct = 0; ct < 64; ++ct) {
            int code = ct * 16 + li;
            int base = code * LDS_STRIDE + g * 8;
            half8 fb0 = *reinterpret_cast<const half8*>(&eL[base]);
            half8 fb1 = *reinterpret_cast<const half8*>(&eL[base + 32]);
            float esqv = *reinterpret_cast<const float*>(&eL[code * LDS_STRIDE + 64]);
            f32x4 acc = {0.f, 0.f, 0.f, 0.f};
            acc = __builtin_amdgcn_mfma_f32_16x16x32_f16(fa0, fb0, acc, 0, 0, 0);
            acc = __builtin_amdgcn_mfma_f32_16x16x32_f16(fa1, fb1, acc, 0, 0, 0);
#pragma unroll
            for (int q = 0; q < 4; ++q) {
                float sc = fmaf(-0.001953125f, acc[q], esqv);   // esq - 2^-9 * dot'
                bool lt = sc < best[q];
                best2[q] = fminf(best2[q], fmaxf(best[q], sc));
                best[q]  = fminf(best[q], sc);
                bidx[q]  = lt ? code : bidx[q];
            }
        }

#pragma unroll
        for (int off = 1; off < 16; off <<= 1) {
#pragma unroll
            for (int q = 0; q < 4; ++q) {
                float nb  = __shfl_xor(best[q], off);
                float nb2 = __shfl_xor(best2[q], off);
                int   nj  = __shfl_xor(bidx[q], off);
                best2[q] = fminf(fminf(best2[q], nb2), fmaxf(best[q], nb));
                bool tk = nb < best[q];
                best[q] = fminf(best[q], nb);
                bidx[q] = tk ? nj : bidx[q];
            }
        }

        if (li < 4) {
            int q = li;
            int row = rt0 + g * 4 + q;
            idx[row] = bidx[q];
            if (best2[q] - best[q] <= mrg[q]) {
                unsigned int p = atomicAdd(cnt, 1u);
                list[p] = row;
            }
        }
    }
}

// ------------------------------------------------------------ refine -------
// R6 rewrite. Block = 256 thr = 4 waves, one flagged row per WAVE.
// z-row wave-uniform -> readfirstlane to SGPRs (no VGPR arrays, no spill).
// Codebook staged in LDS tiles of 128 codes (f32, stride 66 dwords), shared
// by the 4 rows -> 4x less L2 traffic. Dot = bit-exact serial fmaf chain
// (ascending k, single accumulator = sgemm micro-kernel order).
// Lane owns codes tile*128 + u*64 + lane (u=0,1), ascending j within lane;
// cross-lane lexicographic (d, j) reduce = np.argmin semantics.
__global__ __launch_bounds__(256, 4) void vq_refine(const float* __restrict__ z,
                                                    const float* __restrict__ emb,
                                                    const float* __restrict__ esq,
                                                    const int* __restrict__ list,
                                                    const unsigned int* __restrict__ cnt,
                                                    int* __restrict__ idx) {
    __shared__ __align__(8) float eL[128 * 66];   // 33792 B
    int tid  = threadIdx.x;
    int lane = tid & 63;
    int wv   = tid >> 6;
    unsigned int n = *cnt;
    if (n == 0u) return;                           // uniform across grid

    for (unsigned int base = blockIdx.x * 4u; base < n; base += gridDim.x * 4u) {
        unsigned int i = base + wv;
        bool active = (i < n);
        int row = list[active ? i : (n - 1u)];     // dummy-safe
        int b = row >> 15;
        int s = row & (SPAT - 1);
        const float* zb = z + (size_t)b * EDIM * SPAT + s;

        // z-row -> SGPRs (all lanes load identical addresses)
        float zs[EDIM];
#pragma unroll
        for (int c = 0; c < EDIM; ++c) zs[c] = uniform_f32(zb[(size_t)c * SPAT]);

        // A = pairwise8 sum of squares, bit-identical op order, streaming
        float r8[8];
#pragma unroll
        for (int l2 = 0; l2 < 8; ++l2) r8[l2] = __fmul_rn(zs[l2], zs[l2]);
#pragma unroll
        for (int i8 = 8; i8 < 64; i8 += 8) {
#pragma unroll
            for (int l2 = 0; l2 < 8; ++l2)
                r8[l2] = __fadd_rn(r8[l2], __fmul_rn(zs[i8 + l2], zs[i8 + l2]));
        }
        float A = __fadd_rn(
            __fadd_rn(__fadd_rn(r8[0], r8[1]), __fadd_rn(r8[2], r8[3])),
            __fadd_rn(__fadd_rn(r8[4], r8[5]), __fadd_rn(r8[6], r8[7])));

        float bd = 3.4e38f;
        int bj = 0;
        for (int tile = 0; tile < 8; ++tile) {
            __syncthreads();                       // previous tile fully read
            // stage 128 codes: thread -> half a code row (32 floats)
            {
                int cr = tid >> 1;                 // code row within tile
                int h  = (tid & 1) * 32;
                const float* src = emb + (size_t)(tile * 128 + cr) * EDIM + h;
                float* dst = &eL[cr * 66 + h];
#pragma unroll
                for (int m = 0; m < 8; ++m) {
                    float4 v = *reinterpret_cast<const float4*>(src + 4 * m);
                    *reinterpret_cast<float2*>(dst + 4 * m)     = make_float2(v.x, v.y);
                    *reinterpret_cast<float2*>(dst + 4 * m + 2) = make_float2(v.z, v.w);
                }
            }
            __syncthreads();

#pragma unroll
            for (int u = 0; u < 2; ++u) {
                int cc = u * 64 + lane;
                const float* er = &eL[cc * 66];
                float acc = 0.f;
#pragma unroll
                for (int k = 0; k < EDIM; k += 2) {
                    float2 ev = *reinterpret_cast<const float2*>(&er[k]);
                    acc = fmaf(zs[k],     ev.x, acc);   // serial, ascending k
                    acc = fmaf(zs[k + 1], ev.y, acc);
                }
                int j = tile * 128 + cc;
                float tmp = __fadd_rn(A, esq[j]);
                float d = fmaf(-2.f, acc, tmp);    // bit-exact reference d_j
                if (d < bd) { bd = d; bj = j; }    // strict < keeps lowest j
            }
        }

#pragma unroll
        for (int off = 32; off > 0; off >>= 1) {
            float od = __shfl_down(bd, off, 64);
            int oj = __shfl_down(bj, off, 64);
            if (od < bd || (od == bd && oj < bj)) { bd = od; bj = oj; }
        }
        if (active && lane == 0) idx[row] = bj;
    }
}

// ------------------------------------------------------------ gather -------
__global__ __launch_bounds__(256) void vq_gather(const float* __restrict__ emb,
                                                 const int* __restrict__ idx,
                                                 float* __restrict__ out) {
    int row = blockIdx.x * 256 + threadIdx.x;
    int b = row >> 15;
    int s = row & (SPAT - 1);
    int j = idx[row];
    const float4* e4 = reinterpret_cast<const float4*>(emb + j * EDIM);
    float ev[EDIM];
#pragma unroll
    for (int k = 0; k < EDIM / 4; ++k) {
        float4 v = e4[k];
        ev[4 * k + 0] = v.x; ev[4 * k + 1] = v.y;
        ev[4 * k + 2] = v.z; ev[4 * k + 3] = v.w;
    }
    float* ob = out + (size_t)b * EDIM * SPAT + s;
#pragma unroll
    for (int c = 0; c < EDIM; ++c) ob[(size_t)c * SPAT] = ev[c];  // coalesced per c
}

// ------------------------------------------------------------ launch -------
extern "C" void kernel_launch(void* const* d_in, const int* in_sizes, int n_in,
                              void* d_out, int out_size, void* d_ws, size_t ws_size,
                              hipStream_t stream) {
    const float* z   = (const float*)d_in[0];
    const float* emb = (const float*)d_in[1];
    float* out = (float*)d_out;

    // ws: esq f32[1024] | maxesq f32 | cnt u32 (pad to 4KB) | ef f16[1024*64]
    //     | idx i32[NROWS] | list i32[NROWS]   (~1.16 MB)
    char* wp = (char*)d_ws;
    float* esq = (float*)wp;                       wp += 4096;
    float* mxe = (float*)wp;
    unsigned int* cnt = (unsigned int*)(wp + 16);  wp += 4096;
    _Float16* ef = (_Float16*)wp;                  wp += sizeof(_Float16) * ENUM * EDIM;
    int* idx = (int*)wp;                           wp += sizeof(int) * (size_t)NROWS;
    int* list = (int*)wp;

    vq_prep  <<<1,           1024, 0, stream>>>(emb, esq, ef, mxe, cnt);
    vq_score <<<256,         1024, 0, stream>>>(z, ef, esq, mxe, idx, list, cnt);
    vq_refine<<<2048,         256, 0, stream>>>(z, emb, esq, list, cnt, idx);
    vq_gather<<<NROWS / 256,  256, 0, stream>>>(emb, idx, out);
}

// Round 7
// 275.343 us; speedup vs baseline: 1.6814x; 1.1675x over previous
//
#include <hip/hip_runtime.h>
#include <hip/hip_bf16.h>
#include <math.h>

// VectorQuantizer: z (4,64,32,32,32) f32, embedding (1024,64) f32.
// R4: f16 MFMA prefilter (codebook x1024 in LDS, fused best/best2/argmin)
//     + sound per-row margin; flagged rows (~8%) re-scored bit-exactly:
//     d_j = fl32( fl32(A + E_j) - 2*serialFMA(z,e_j) ), pairwise8 sums,
//     np.argmin lowest-index ties.
// R6: refine LDS-tile version: 295->154 us but bank-conflicted (4.9M) and
//     barrier/latency-bound (VALUBusy 15%).
// R7: refine v3 — one flagged row per LANE (zr[64] per-lane VGPRs, no LDS,
//     no barriers), wave scans a 128-code segment with wave-uniform e-loads
//     (scalar-cache path), global argmin via packed (d_bits<<32|j) u64
//     atomicMin: monotone for d>0 and ties resolve to lowest j = np.argmin.

#define ENUM 1024
#define EDIM 64
#define SPAT 32768           // 32*32*32
#define NROWS 131072         // 4 * SPAT
#define LDS_STRIDE 72        // score: halves per code row (64 data + esq + pad)
#define RSEG 8               // refine code segments
#define RCODES (ENUM / RSEG) // 128 codes per segment

typedef _Float16 half8 __attribute__((ext_vector_type(8)));
typedef float f32x4 __attribute__((ext_vector_type(4)));
typedef unsigned short us8 __attribute__((ext_vector_type(8)));

// numpy pairwise_sum for n=64: 8 stride-8 accumulators, then tree combine.
__device__ __forceinline__ float pairwise64(const float* t) {
    float r[8];
#pragma unroll
    for (int l = 0; l < 8; ++l) r[l] = t[l];
#pragma unroll
    for (int i = 8; i < 64; i += 8) {
#pragma unroll
        for (int l = 0; l < 8; ++l) r[l] = __fadd_rn(r[l], t[i + l]);
    }
    return __fadd_rn(__fadd_rn(__fadd_rn(r[0], r[1]), __fadd_rn(r[2], r[3])),
                     __fadd_rn(__fadd_rn(r[4], r[5]), __fadd_rn(r[6], r[7])));
}

// ---------------------------------------------------------------- prep -----
__global__ __launch_bounds__(1024) void vq_prep(const float* __restrict__ emb,
                                                float* __restrict__ esq_g,
                                                _Float16* __restrict__ ef,
                                                float* __restrict__ maxesq,
                                                unsigned int* __restrict__ cnt) {
    __shared__ float red[1024];
    int j = threadIdx.x;
    const float4* ep = reinterpret_cast<const float4*>(emb + j * EDIM);
    float t[EDIM];
#pragma unroll
    for (int kk = 0; kk < 16; ++kk) {
        float4 v = ep[kk];
        t[4 * kk + 0] = __fmul_rn(v.x, v.x);
        t[4 * kk + 1] = __fmul_rn(v.y, v.y);
        t[4 * kk + 2] = __fmul_rn(v.z, v.z);
        t[4 * kk + 3] = __fmul_rn(v.w, v.w);
        ef[j * EDIM + 4 * kk + 0] = (_Float16)(v.x * 1024.0f);
        ef[j * EDIM + 4 * kk + 1] = (_Float16)(v.y * 1024.0f);
        ef[j * EDIM + 4 * kk + 2] = (_Float16)(v.z * 1024.0f);
        ef[j * EDIM + 4 * kk + 3] = (_Float16)(v.w * 1024.0f);
    }
    float e2 = pairwise64(t);
    esq_g[j] = e2;
    red[j] = e2;
    __syncthreads();
    for (int s = 512; s > 0; s >>= 1) {
        if (j < s) red[j] = fmaxf(red[j], red[j + s]);
        __syncthreads();
    }
    if (j == 0) { *maxesq = red[0]; *cnt = 0u; }
}

// ------------------------------------------------------------- score -------
// (R4 structure; R7 adds only the pk[row] sentinel init on flagging)
__global__ __launch_bounds__(1024, 4) void vq_score(const float* __restrict__ z,
                                                    const _Float16* __restrict__ ef,
                                                    const float* __restrict__ esq_g,
                                                    const float* __restrict__ maxesq,
                                                    int* __restrict__ idx,
                                                    int* __restrict__ list,
                                                    unsigned int* __restrict__ cnt,
                                                    unsigned long long* __restrict__ pk) {
    __shared__ __align__(16) unsigned short eL[ENUM * LDS_STRIDE];  // 147456 B

    int tid = threadIdx.x;
    {
        const unsigned short* src = reinterpret_cast<const unsigned short*>(ef) + tid * EDIM;
#pragma unroll
        for (int i = 0; i < 8; ++i)
            *reinterpret_cast<us8*>(&eL[tid * LDS_STRIDE + i * 8]) =
                *reinterpret_cast<const us8*>(src + i * 8);
        *reinterpret_cast<float*>(&eL[tid * LDS_STRIDE + 64]) = esq_g[tid];
    }
    __syncthreads();

    int l  = tid & 63;
    int w  = tid >> 6;          // wave 0..15
    int g  = l >> 4;            // k-group 0..3
    int li = l & 15;            // row (A) / col (B) within tile
    float mxe = *maxesq;

    for (int c = 0; c < 2; ++c) {
        int rt0 = blockIdx.x * 512 + w * 32 + c * 16;   // row-tile base
        int b = rt0 >> 15;
        int s0 = (rt0 & (SPAT - 1)) + li;
        const float* zp = z + (size_t)b * EDIM * SPAT + s0;
        int o = g * 8;

        float za[8], zb8[8];
#pragma unroll
        for (int i = 0; i < 8; ++i) za[i]  = zp[(size_t)(o + i) * SPAT];
#pragma unroll
        for (int i = 0; i < 8; ++i) zb8[i] = zp[(size_t)(32 + o + i) * SPAT];

        float pa = 0.f;
#pragma unroll
        for (int i = 0; i < 8; ++i) pa += za[i] * za[i] + zb8[i] * zb8[i];
        pa += __shfl_xor(pa, 16);
        pa += __shfl_xor(pa, 32);

        half8 fa0, fa1;
#pragma unroll
        for (int i = 0; i < 8; ++i) { fa0[i] = (_Float16)za[i]; fa1[i] = (_Float16)zb8[i]; }

        float mrg[4];
#pragma unroll
        for (int q = 0; q < 4; ++q) {
            float Aq = __shfl(pa, g * 4 + q);
            mrg[q] = fmaf(sqrtf(Aq * mxe), 0.00390625f, 3.0e-5f);
        }

        float best[4], best2[4];
        int bidx[4];
#pragma unroll
        for (int q = 0; q < 4; ++q) { best[q] = 3.4e38f; best2[q] = 3.4e38f; bidx[q] = 0; }

        for (int ct = 0; ct < 64; ++ct) {
            int code = ct * 16 + li;
            int base = code * LDS_STRIDE + g * 8;
            half8 fb0 = *reinterpret_cast<const half8*>(&eL[base]);
            half8 fb1 = *reinterpret_cast<const half8*>(&eL[base + 32]);
            float esqv = *reinterpret_cast<const float*>(&eL[code * LDS_STRIDE + 64]);
            f32x4 acc = {0.f, 0.f, 0.f, 0.f};
            acc = __builtin_amdgcn_mfma_f32_16x16x32_f16(fa0, fb0, acc, 0, 0, 0);
            acc = __builtin_amdgcn_mfma_f32_16x16x32_f16(fa1, fb1, acc, 0, 0, 0);
#pragma unroll
            for (int q = 0; q < 4; ++q) {
                float sc = fmaf(-0.001953125f, acc[q], esqv);   // esq - 2^-9 * dot'
                bool lt = sc < best[q];
                best2[q] = fminf(best2[q], fmaxf(best[q], sc));
                best[q]  = fminf(best[q], sc);
                bidx[q]  = lt ? code : bidx[q];
            }
        }

#pragma unroll
        for (int off = 1; off < 16; off <<= 1) {
#pragma unroll
            for (int q = 0; q < 4; ++q) {
                float nb  = __shfl_xor(best[q], off);
                float nb2 = __shfl_xor(best2[q], off);
                int   nj  = __shfl_xor(bidx[q], off);
                best2[q] = fminf(fminf(best2[q], nb2), fmaxf(best[q], nb));
                bool tk = nb < best[q];
                best[q] = fminf(best[q], nb);
                bidx[q] = tk ? nj : bidx[q];
            }
        }

        if (li < 4) {
            int q = li;
            int row = rt0 + g * 4 + q;
            idx[row] = bidx[q];
            if (best2[q] - best[q] <= mrg[q]) {
                pk[row] = 0xFFFFFFFFFFFFFFFFull;     // sentinel for atomicMin
                unsigned int p = atomicAdd(cnt, 1u);
                list[p] = row;
            }
        }
    }
}

// ------------------------------------------------------------ refine -------
// R7: one flagged row per LANE; wave owns a 128-code segment (blockIdx.y).
// zr[64] per-lane VGPRs; e-loads wave-uniform (scalar-cache path); dot is
// the bit-exact serial-ascending fmaf chain; global lexicographic argmin via
// packed (d_bits<<32 | j) u64 atomicMin (d>0 -> bit-monotone; ties -> low j).
__global__ __launch_bounds__(256, 2) void vq_refine(const float* __restrict__ z,
                                                    const float* __restrict__ emb,
                                                    const float* __restrict__ esq,
                                                    const int* __restrict__ list,
                                                    const unsigned int* __restrict__ cnt,
                                                    unsigned long long* __restrict__ pk) {
    int lane = threadIdx.x & 63;
    int wv   = threadIdx.x >> 6;                    // wave in block (0..3)
    int j0   = blockIdx.y * RCODES;                 // segment base
    unsigned int n = *cnt;

    for (unsigned int base = (blockIdx.x * 4u + wv) * 64u; base < n;
         base += gridDim.x * 4u * 64u) {
        unsigned int i = base + (unsigned int)lane;
        bool active = (i < n);
        int row = list[active ? i : n - 1u];
        int b = row >> 15;
        int s = row & (SPAT - 1);
        const float* zb = z + (size_t)b * EDIM * SPAT + s;

        float zr[EDIM];
#pragma unroll
        for (int c = 0; c < EDIM; ++c) zr[c] = zb[(size_t)c * SPAT];

        // A = pairwise8 sum of squares (streaming: zr + r8 live only)
        float r8[8];
#pragma unroll
        for (int l2 = 0; l2 < 8; ++l2) r8[l2] = __fmul_rn(zr[l2], zr[l2]);
#pragma unroll
        for (int i8 = 8; i8 < 64; i8 += 8) {
#pragma unroll
            for (int l2 = 0; l2 < 8; ++l2)
                r8[l2] = __fadd_rn(r8[l2], __fmul_rn(zr[i8 + l2], zr[i8 + l2]));
        }
        float A = __fadd_rn(
            __fadd_rn(__fadd_rn(r8[0], r8[1]), __fadd_rn(r8[2], r8[3])),
            __fadd_rn(__fadd_rn(r8[4], r8[5]), __fadd_rn(r8[6], r8[7])));

        float bd = 3.4e38f;
        int bj = 0;
        for (int jo = 0; jo < RCODES; jo += 2) {    // 2 j-chains for ILP
            int ja = j0 + jo;
            int jb = ja + 1;
            const float4* ea = reinterpret_cast<const float4*>(emb + (size_t)ja * EDIM);
            const float4* eb = reinterpret_cast<const float4*>(emb + (size_t)jb * EDIM);
            float acca = 0.f, accb = 0.f;
#pragma unroll
            for (int kk = 0; kk < 16; ++kk) {       // serial ascending k per chain
                float4 va = ea[kk];
                float4 vb = eb[kk];
                acca = fmaf(zr[4 * kk + 0], va.x, acca);
                acca = fmaf(zr[4 * kk + 1], va.y, acca);
                acca = fmaf(zr[4 * kk + 2], va.z, acca);
                acca = fmaf(zr[4 * kk + 3], va.w, acca);
                accb = fmaf(zr[4 * kk + 0], vb.x, accb);
                accb = fmaf(zr[4 * kk + 1], vb.y, accb);
                accb = fmaf(zr[4 * kk + 2], vb.z, accb);
                accb = fmaf(zr[4 * kk + 3], vb.w, accb);
            }
            float da = fmaf(-2.f, acca, __fadd_rn(A, esq[ja]));  // bit-exact ref d
            float db = fmaf(-2.f, accb, __fadd_rn(A, esq[jb]));
            if (da < bd) { bd = da; bj = ja; }      // ja < jb: lowest-j ties kept
            if (db < bd) { bd = db; bj = jb; }
        }

        if (active) {
            unsigned long long p =
                ((unsigned long long)__float_as_uint(bd) << 32) | (unsigned int)bj;
            atomicMin(&pk[row], p);
        }
    }
}

// ------------------------------------------------------------ unpack -------
__global__ __launch_bounds__(256) void vq_unpack(const int* __restrict__ list,
                                                 const unsigned int* __restrict__ cnt,
                                                 const unsigned long long* __restrict__ pk,
                                                 int* __restrict__ idx) {
    unsigned int n = *cnt;
    for (unsigned int i = blockIdx.x * 256 + threadIdx.x; i < n;
         i += gridDim.x * 256) {
        int row = list[i];
        idx[row] = (int)(pk[row] & 0xFFFFFFFFull);
    }
}

// ------------------------------------------------------------ gather -------
__global__ __launch_bounds__(256) void vq_gather(const float* __restrict__ emb,
                                                 const int* __restrict__ idx,
                                                 float* __restrict__ out) {
    int row = blockIdx.x * 256 + threadIdx.x;
    int b = row >> 15;
    int s = row & (SPAT - 1);
    int j = idx[row];
    const float4* e4 = reinterpret_cast<const float4*>(emb + j * EDIM);
    float ev[EDIM];
#pragma unroll
    for (int k = 0; k < EDIM / 4; ++k) {
        float4 v = e4[k];
        ev[4 * k + 0] = v.x; ev[4 * k + 1] = v.y;
        ev[4 * k + 2] = v.z; ev[4 * k + 3] = v.w;
    }
    float* ob = out + (size_t)b * EDIM * SPAT + s;
#pragma unroll
    for (int c = 0; c < EDIM; ++c) ob[(size_t)c * SPAT] = ev[c];  // coalesced per c
}

// ------------------------------------------------------------ launch -------
extern "C" void kernel_launch(void* const* d_in, const int* in_sizes, int n_in,
                              void* d_out, int out_size, void* d_ws, size_t ws_size,
                              hipStream_t stream) {
    const float* z   = (const float*)d_in[0];
    const float* emb = (const float*)d_in[1];
    float* out = (float*)d_out;

    // ws: esq f32[1024] | maxesq f32, cnt u32 (4KB) | ef f16[1024*64]
    //     | idx i32[NROWS] | list i32[NROWS] | pk u64[NROWS]   (~2.2 MB)
    char* wp = (char*)d_ws;
    float* esq = (float*)wp;                       wp += 4096;
    float* mxe = (float*)wp;
    unsigned int* cnt = (unsigned int*)(wp + 16);  wp += 4096;
    _Float16* ef = (_Float16*)wp;                  wp += sizeof(_Float16) * ENUM * EDIM;
    int* idx = (int*)wp;                           wp += sizeof(int) * (size_t)NROWS;
    int* list = (int*)wp;                          wp += sizeof(int) * (size_t)NROWS;
    unsigned long long* pk = (unsigned long long*)wp;

    vq_prep  <<<1,           1024, 0, stream>>>(emb, esq, ef, mxe, cnt);
    vq_score <<<256,         1024, 0, stream>>>(z, ef, esq, mxe, idx, list, cnt, pk);
    dim3 rgrid(64, RSEG);
    vq_refine<<<rgrid,        256, 0, stream>>>(z, emb, esq, list, cnt, pk);
    vq_unpack<<<128,          256, 0, stream>>>(list, cnt, pk, idx);
    vq_gather<<<NROWS / 256,  256, 0, stream>>>(emb, idx, out);
}